// Round 7
// baseline (2867.334 us; speedup 1.0000x reference)
//
#include <hip/hip_runtime.h>

#define NPB 8192
#define NB 8
#define MQ 2048
#define FD 64
#define KN 32
#define CD 128
#define NQ (NB*MQ)
#define CAP 512
#define NCB 124                               // consumer blocks (1024 thr = 8 units)
#define NUNITS (NCB*8)                        // 992 units of 128 threads
#define UPC (NUNITS/NB)                       // 124 units per cloud
#define QITERS ((MQ + UPC - 1) / UPC)         // 17 rounds, tq = r*124+ui
#define PSTRIDE 16                            // progress padded to 64B/cloud

typedef unsigned long long ull;
typedef float v2f __attribute__((ext_vector_type(2)));

// LDS-only block barrier: orders LDS ops across the block WITHOUT draining
// vmcnt (global stores keep flying). Only LDS data (slot[]) crosses this
// barrier in the FPS loop, so lgkmcnt(0) is sufficient.
#define LDS_BARRIER() asm volatile("s_waitcnt lgkmcnt(0)\n\ts_barrier" ::: "memory")

// exact (non-FMA) squared distance, matching ((dx*dx + dy*dy) + dz*dz) in f32
__device__ __forceinline__ float dist2(float ax, float ay, float az,
                                       float bx, float by, float bz) {
    float dx = __fsub_rn(ax, bx);
    float dy = __fsub_rn(ay, by);
    float dz = __fsub_rn(az, bz);
    return __fadd_rn(__fadd_rn(__fmul_rn(dx, dx), __fmul_rn(dy, dy)), __fmul_rn(dz, dz));
}

// ---- f64-as-u64 ordered max -------------------------------------------------
// Key = (dmin_bits<<32) | ~idx. Top bit is always 0 and the f64 exponent field
// never reaches all-ones because dmin is a non-NaN f32 (<= 0x7f800000). So every
// key is a positive finite double; for positive finite doubles IEEE ordering ==
// unsigned ordering of the bits. One v_max_f64 replaces 5-op u64 cmp+cndmask.
__device__ __forceinline__ double key_as_f64(ull k) {
    return __longlong_as_double((long long)k);
}
__device__ __forceinline__ ull key_as_u64(double d) {
    return (ull)__double_as_longlong(d);
}

template <int CTRL>
__device__ __forceinline__ double dpp_max_f64_step(double key) {
    ull u = key_as_u64(key);
    int lo = (int)(unsigned)u, hi = (int)(u >> 32);
    int lo2 = __builtin_amdgcn_update_dpp(0, lo, CTRL, 0xf, 0xf, false);
    int hi2 = __builtin_amdgcn_update_dpp(0, hi, CTRL, 0xf, 0xf, false);
    double o = key_as_f64(((ull)(unsigned)hi2 << 32) | (unsigned)lo2);
    // lanes with no source get old=0 -> +0.0, which never beats a real key (>0)
    return fmax(key, o);
}

// 6-step full-wave (64-lane) max reduce via DPP; result valid in lane 63.
__device__ __forceinline__ double dpp_max_f64(double key) {
    key = dpp_max_f64_step<0x111>(key);  // row_shr:1
    key = dpp_max_f64_step<0x112>(key);  // row_shr:2
    key = dpp_max_f64_step<0x114>(key);  // row_shr:4
    key = dpp_max_f64_step<0x118>(key);  // row_shr:8
    key = dpp_max_f64_step<0x142>(key);  // row_bcast15
    key = dpp_max_f64_step<0x143>(key);  // row_bcast31
    return key;
}

// 4-step reduce when values are replicated within each 4-lane group
// (16 distinct candidates at lanes g*4..g*4+3); result valid in lane 63.
__device__ __forceinline__ double dpp_max_f64_groups4(double key) {
    key = dpp_max_f64_step<0x114>(key);  // row_shr:4
    key = dpp_max_f64_step<0x118>(key);  // row_shr:8
    key = dpp_max_f64_step<0x142>(key);  // row_bcast15
    key = dpp_max_f64_step<0x143>(key);  // row_bcast31
    return key;
}

__device__ __forceinline__ unsigned morton9(float x, float y, float z) {
    unsigned cx = (unsigned)min(7, max(0, (int)(x * 8.0f)));
    unsigned cy = (unsigned)min(7, max(0, (int)(y * 8.0f)));
    unsigned cz = (unsigned)min(7, max(0, (int)(z * 8.0f)));
    return (cx & 1) | ((cy & 1) << 1) | ((cz & 1) << 2)
         | ((cx & 2) << 2) | ((cy & 2) << 3) | ((cz & 2) << 4)
         | ((cx & 4) << 4) | ((cy & 4) << 5) | ((cz & 4) << 6);
}

struct __align__(16) FpsSlot {         // 48 B: staggers 16 slots across LDS banks
    ull key;                           // (dmin_bits << 32) | ~orig_idx
    float x, y, z;
    float pad[7];
};
struct FpsSM {
    float2 sxy[NPB];                   // 64 KB
    float sz[NPB];                     // 32 KB
    unsigned sidx[NPB];                // 32 KB (morton-bucketed point order)
    FpsSlot slot[2][16];               // 1.5 KB double-buffered candidates
    unsigned hist[512];                // counting-sort histogram
    unsigned off[512];                 // prefix/pong buffer
};
struct UnitSM {
    float msg[KN][68];                 // 8704 B, 16-aligned (first member)
    ull buf[CAP];                      // 4096 B
    int nb[KN];
    int scnt;
    int pad;
};
union SMU {
    FpsSM f;
    UnitSM u[8];
};

// (1024, 4): 4 waves/EU min occupancy -> 128-VGPR cap. Round-5's plain
// __launch_bounds__(1024) clamped to 64 VGPR and spilled the consumer's
// w[68] to scratch (1.7 GB FETCH). This is the fix that makes 16-wave FPS
// (8 pts/thread scan) testable.
__global__ __launch_bounds__(1024, 4) void mega_kernel(const float* __restrict__ xin,
                                                       const float* __restrict__ pos,
                                                       const float* __restrict__ W1,
                                                       const float* __restrict__ b1,
                                                       int* __restrict__ samp,
                                                       int* __restrict__ progress,
                                                       float* __restrict__ out) {
    __shared__ SMU sm;
    const int tid = threadIdx.x;

    if (blockIdx.x < NB) {
        // ======================= FPS producer (blocks 0..7) =======================
        // 16 waves scan 512-point Morton-compact regions (8 pts/thread).
        const int b = blockIdx.x;
        const int wv = tid >> 6, lane = tid & 63;
        const float* p0 = pos + (size_t)b * NPB * 3;

        // ---- stage positions + morton histogram ----
        if (tid < 512) sm.f.hist[tid] = 0;
        __syncthreads();
        for (int i = tid; i < NPB; i += 1024) {
            float x = p0[i * 3 + 0];
            float y = p0[i * 3 + 1];
            float z = p0[i * 3 + 2];
            sm.f.sxy[i] = make_float2(x, y);
            sm.f.sz[i] = z;
            atomicAdd(&sm.f.hist[morton9(x, y, z)], 1);
        }
        __syncthreads();

        // ---- seed "previous" slots so t==0 takes the uniform path (winner idx 0) ----
        if (tid < 16) {
            FpsSlot* d = &sm.f.slot[1][tid];
            d->key = ((ull)0x7f800000u << 32) | 0xFFFFFFFFu;
            d->x = sm.f.sxy[0].x;
            d->y = sm.f.sxy[0].y;
            d->z = sm.f.sz[0];
        }

        // ---- exclusive prefix over 512 bins (Hillis-Steele, ping-pong) ----
        unsigned hval = (tid < 512) ? sm.f.hist[tid] : 0u;
        unsigned* src = sm.f.hist;
        unsigned* dst = sm.f.off;
        #pragma unroll 1
        for (int d = 1; d < 512; d <<= 1) {
            unsigned v = 0;
            if (tid < 512) {
                v = src[tid];
                if (tid >= d) v += src[tid - d];
            }
            __syncthreads();
            if (tid < 512) dst[tid] = v;
            __syncthreads();
            unsigned* tmp = src; src = dst; dst = tmp;
        }
        if (tid < 512) dst[tid] = src[tid] - hval;   // exclusive prefix -> cursor
        unsigned* cursor = dst;
        __syncthreads();

        // ---- scatter: morton-bucketed point order ----
        for (int i = tid; i < NPB; i += 1024) {
            float2 xy = sm.f.sxy[i];
            unsigned m = morton9(xy.x, xy.y, sm.f.sz[i]);
            unsigned p = atomicAdd(&cursor[m], 1);
            sm.f.sidx[p] = (unsigned)i;
        }
        __syncthreads();

        // ---- register staging: 8 spatially-compact points per thread ----
        // Region->wave map (5w mod 16): spreads regions so co-SIMD waves own
        // distant space and are rarely active together.
        const int region = (wv * 5) & 15;
        const unsigned* sp = &sm.f.sidx[region * 512 + lane * 8];
        v2f px2[4], py2[4], pz2[4], dmin2[4];
        unsigned norig[8];
        const float inf = __builtin_huge_valf();
        float bx0 = inf, bx1 = -inf;
        float by0 = inf, by1 = -inf;
        float bz0 = inf, bz1 = -inf;
        #pragma unroll
        for (int i = 0; i < 4; i++) {
            unsigned o0 = sp[2 * i + 0];
            unsigned o1 = sp[2 * i + 1];
            norig[2 * i + 0] = ~o0;
            norig[2 * i + 1] = ~o1;
            float2 a = sm.f.sxy[o0], c2 = sm.f.sxy[o1];
            float za = sm.f.sz[o0], zc = sm.f.sz[o1];
            px2[i] = (v2f){a.x, c2.x};
            py2[i] = (v2f){a.y, c2.y};
            pz2[i] = (v2f){za, zc};
            dmin2[i] = (v2f){inf, inf};
            bx0 = fminf(bx0, fminf(a.x, c2.x)); bx1 = fmaxf(bx1, fmaxf(a.x, c2.x));
            by0 = fminf(by0, fminf(a.y, c2.y)); by1 = fmaxf(by1, fmaxf(a.y, c2.y));
            bz0 = fminf(bz0, fminf(za, zc));    bz1 = fmaxf(bz1, fmaxf(za, zc));
        }
        double mykey = key_as_f64((ull)0x7f800000u << 32);  // dmin=+INF -> scans at t=0
        ull cachedkey = 0;
        float cachedx = 0.f, cachedy = 0.f, cachedz = 0.f;
        __syncthreads();

        for (int t = 0; t < MQ; t++) {
            // ---- resolve global winner: lane-group g (4 lanes) reads slot g ----
            const FpsSlot* srd = &sm.f.slot[(t - 1) & 1][lane >> 2];
            ulonglong2 rv = *(const ulonglong2*)srd;   // key | (x,y)
            float gzf = srd->z;
            ull kg = rv.x;
            double krd = dpp_max_f64_groups4(key_as_f64(kg));
            ull krb = key_as_u64(krd);
            unsigned whi = (unsigned)__builtin_amdgcn_readlane((int)(krb >> 32), 63);
            unsigned wlo = (unsigned)__builtin_amdgcn_readlane((int)(unsigned)krb, 63);
            ull wk = ((ull)whi << 32) | wlo;
            int last = (int)((~wlo) & (NPB - 1));
            ull iswin = __ballot(kg == wk);
            int wl = __ffsll((long long)iswin) - 1;
            int gxi = (int)(unsigned)rv.y;
            int gyi = (int)(rv.y >> 32);
            float lx = __int_as_float(__builtin_amdgcn_readlane(gxi, wl));
            float ly = __int_as_float(__builtin_amdgcn_readlane(gyi, wl));
            float lz = __int_as_float(__builtin_amdgcn_readlane(__float_as_int(gzf), wl));

            // publisher: plain store per iter, release-publish every 16 iters.
            if (tid == 960) {
                samp[b * MQ + t] = last;
                if ((t & 15) == 15)
                    __hip_atomic_store(&progress[b * PSTRIDE], t + 1, __ATOMIC_RELEASE,
                                       __HIP_MEMORY_SCOPE_AGENT);
            }

            // conservative lower bound of d2(last, any point in this thread's bbox)
            float ddx = fmaxf(fmaxf(bx0 - lx, lx - bx1), 0.0f);
            float ddy = fmaxf(fmaxf(by0 - ly, ly - by1), 0.0f);
            float ddz = fmaxf(fmaxf(bz0 - lz, lz - bz1), 0.0f);
            float dlb = ddx * ddx + ddy * ddy + ddz * ddz;
            float cm = __uint_as_float((unsigned)(key_as_u64(mykey) >> 32));
            bool act = __fmul_rn(0.999f, dlb) < cm;

            if (__any(act)) {
                double oldkey = mykey;
                if (act) {
                    // contract(off): keep mul,mul,mul,add,add exactly like the
                    // reference (((dx*dx + dy*dy) + dz*dz)).
                    #pragma clang fp contract(off)
                    double ba = 0.0, bb = 0.0;
                    #pragma unroll
                    for (int i = 0; i < 4; i++) {
                        v2f dx = px2[i] - lx;
                        v2f dy = py2[i] - ly;
                        v2f dz = pz2[i] - lz;
                        v2f d2v = (dx * dx + dy * dy) + dz * dz;
                        float d0 = fminf(dmin2[i].x, d2v.x);
                        float d1 = fminf(dmin2[i].y, d2v.y);
                        dmin2[i] = (v2f){d0, d1};
                        double k0 = key_as_f64(((ull)__float_as_uint(d0) << 32) | norig[2 * i + 0]);
                        double k1 = key_as_f64(((ull)__float_as_uint(d1) << 32) | norig[2 * i + 1]);
                        ba = fmax(ba, k0);
                        bb = fmax(bb, k1);
                    }
                    mykey = fmax(ba, bb);
                }
                // skip the wave-reduce when no lane's best changed (bit-exact):
                // the wave max and its cached coords are then still valid.
                if (!__all(mykey == oldkey)) {
                    double w = dpp_max_f64(mykey);
                    ull wb = key_as_u64(w);
                    unsigned chi = (unsigned)__builtin_amdgcn_readlane((int)(wb >> 32), 63);
                    unsigned clo = (unsigned)__builtin_amdgcn_readlane((int)(unsigned)wb, 63);
                    cachedkey = ((ull)chi << 32) | clo;
                    int wi = (int)((~clo) & (NPB - 1));
                    float2 cxy = sm.f.sxy[wi];          // uniform addr -> broadcast read
                    cachedx = cxy.x;
                    cachedy = cxy.y;
                    cachedz = sm.f.sz[wi];
                }
            }
            // write (possibly cached) candidate slot for this iteration
            if (lane == 63) {
                FpsSlot* d = &sm.f.slot[t & 1][wv];
                ulonglong2 wv2;
                wv2.x = cachedkey;
                wv2.y = ((ull)(unsigned)__float_as_int(cachedy) << 32)
                      | (unsigned)__float_as_int(cachedx);
                *(ulonglong2*)d = wv2;              // ds_write_b128
                d->z = cachedz;                     // ds_write_b32
            }
            LDS_BARRIER();   // orders the LDS slots; does NOT drain global stores
        }
        return;
    }

    // ================== consumers: ball query + MLP + tail outputs ==================
    const int c = blockIdx.x - NB;         // 0..123
    const int unit = tid >> 7;             // 0..7
    const int ut = tid & 127;              // thread-in-unit
    UnitSM& U = sm.u[unit];
    const int g = c * 8 + unit;            // global unit id, 0..991
    const int b = g & 7;                   // cloud owned by this unit (== unit)
    const int ui = g >> 3;                 // 0..123 slot within cloud (== c)
    const float RR = (float)(0.1 * 0.1);
    const float* P = pos + (size_t)b * NPB * 3;

    // per-channel weights, hoisted across queries
    float w[68];
    #pragma unroll
    for (int f = 0; f < 67; f++) w[f] = W1[f * CD + ut];
    w[67] = 0.0f;
    const float bias = b1[ut];

    for (int r = 0; r < QITERS; r++) {
        // pipelined mapping: round r needs FPS progress only up to 124*(r+1),
        // so consumer work overlaps FPS instead of bursting after it finishes.
        const int tq = r * UPC + ui;
        const bool active = tq < MQ;
        const int q = (b << 11) + tq;
        int s = 0;
        float qx = 0.f, qy = 0.f, qz = 0.f;

        if (active && ut == 0) {
            // single poller per unit: relaxed agent load + one acquire fence;
            // the following __syncthreads orders it for the whole unit.
            while (__hip_atomic_load(&progress[b * PSTRIDE], __ATOMIC_RELAXED,
                                     __HIP_MEMORY_SCOPE_AGENT) < tq + 1) {}
            __builtin_amdgcn_fence(__ATOMIC_ACQUIRE, "agent");
            U.scnt = 0;
        }
        __syncthreads();                                   // barrier 1

        if (active) {
            s = samp[q] & (NPB - 1);
            qx = P[s * 3 + 0]; qy = P[s * 3 + 1]; qz = P[s * 3 + 2];
            for (int p = ut; p < NPB; p += 128) {
                float xx = P[p * 3 + 0];
                float yy = P[p * 3 + 1];
                float zz = P[p * 3 + 2];
                float d2v = dist2(qx, qy, qz, xx, yy, zz);
                if (d2v <= RR) {
                    int slot = atomicAdd(&U.scnt, 1);
                    if (slot < CAP)
                        U.buf[slot] = ((ull)__float_as_uint(d2v) << 32) | (unsigned)p;
                }
            }
        }
        __syncthreads();                                   // barrier 2

        int n = 0, nk = 0;
        if (active) {
            n = U.scnt; if (n > CAP) n = CAP;
            nk = (n < KN) ? n : KN;
        }
        if (active && ut < 64) {
            if (n <= 64) {
                // fast path: 64-key bitonic sort in the unit's first wave
                ull key = (ut < n) ? U.buf[ut] : ~0ULL;
                #pragma unroll
                for (int k = 2; k <= 64; k <<= 1) {
                    #pragma unroll
                    for (int j = k >> 1; j > 0; j >>= 1) {
                        ull o = __shfl_xor(key, (unsigned)j, 64);
                        bool ascending = ((ut & k) == 0);
                        bool upper = ((ut & j) != 0);
                        bool keepMin = (ascending != upper);
                        ull mn = (o < key) ? o : key;
                        ull mx = (o < key) ? key : o;
                        key = keepMin ? mn : mx;
                    }
                }
                if (ut < nk) U.nb[ut] = ((int)(unsigned)key) & (NPB - 1);
            } else {
                // slow path (rare): nk rounds of wave-min selection
                ull ck[CAP / 64];
                #pragma unroll
                for (int i = 0; i < CAP / 64; i++) {
                    int sl = ut + i * 64;
                    ck[i] = (sl < n) ? U.buf[sl] : ~0ULL;
                }
                for (int rr = 0; rr < nk; rr++) {
                    ull lm = ck[0];
                    int li = 0;
                    #pragma unroll
                    for (int i = 1; i < CAP / 64; i++) {
                        if (ck[i] < lm) { lm = ck[i]; li = i; }
                    }
                    ull gm = lm;
                    #pragma unroll
                    for (int off = 1; off < 64; off <<= 1) {
                        ull o = __shfl_xor(gm, off, 64);
                        gm = (o < gm) ? o : gm;
                    }
                    ull won = __ballot(lm == gm);
                    int wlane = __ffsll((long long)won) - 1;
                    if (ut == wlane) ck[li] = ~0ULL;
                    if (ut == 0) U.nb[rr] = ((int)(unsigned)gm) & (NPB - 1);
                }
            }
        }
        __syncthreads();                                   // barrier 3

        if (active) {
            const int lane64 = ut & 63, half = ut >> 6;
            for (int k = half; k < nk; k += 2) {
                int p = U.nb[k];
                U.msg[k][lane64] = xin[((size_t)(b * NPB + p)) * FD + lane64];
            }
            if (ut < nk) {
                int p = U.nb[ut];
                U.msg[ut][64] = __fsub_rn(P[p * 3 + 0], qx);
                U.msg[ut][65] = __fsub_rn(P[p * 3 + 1], qy);
                U.msg[ut][66] = __fsub_rn(P[p * 3 + 2], qz);
                U.msg[ut][67] = 0.0f;
            }
        }
        __syncthreads();                                   // barrier 4

        if (active) {
            float acc = 0.0f;   // relu >= 0 and nk >= 1 (self), so 0 is the max identity
            for (int k = 0; k < nk; k++) {
                float s0 = 0.f, s1 = 0.f, s2 = 0.f, s3 = 0.f;
                #pragma unroll
                for (int f4 = 0; f4 < 17; f4++) {
                    float4 mv = *(const float4*)&U.msg[k][f4 * 4];
                    s0 = fmaf(mv.x, w[f4 * 4 + 0], s0);
                    s1 = fmaf(mv.y, w[f4 * 4 + 1], s1);
                    s2 = fmaf(mv.z, w[f4 * 4 + 2], s2);
                    s3 = fmaf(mv.w, w[f4 * 4 + 3], s3);
                }
                float h = (s0 + s1) + (s2 + s3) + bias;
                h = fmaxf(h, 0.0f);
                acc = fmaxf(acc, h);
            }
            out[(size_t)q * CD + ut] = acc;
            if (ut == 0) {
                float* qp = out + (size_t)NQ * CD;
                qp[q * 3 + 0] = qx;
                qp[q * 3 + 1] = qy;
                qp[q * 3 + 2] = qz;
                float* bo = qp + (size_t)NQ * 3;
                bo[q] = (float)b;
                float* io = bo + NQ;
                io[q] = (float)(b * NPB + s);
            }
        }
    }
}

extern "C" void kernel_launch(void* const* d_in, const int* in_sizes, int n_in,
                              void* d_out, int out_size, void* d_ws, size_t ws_size,
                              hipStream_t stream) {
    const float* x   = (const float*)d_in[0];
    const float* pos = (const float*)d_in[1];
    const float* W1  = (const float*)d_in[3];
    const float* b1  = (const float*)d_in[4];
    float* out = (float*)d_out;

    int* samp = (int*)d_ws;                     // NQ ints (64B-aligned base)
    int* progress = samp + NQ;                  // NB*PSTRIDE ints (1 line/cloud)

    hipMemsetAsync(progress, 0, NB * PSTRIDE * sizeof(int), stream);
    mega_kernel<<<NB + NCB, 1024, 0, stream>>>(x, pos, W1, b1, samp, progress, out);
}

// Round 8
// 1521.336 us; speedup vs baseline: 1.8847x; 1.8847x over previous
//
#include <hip/hip_runtime.h>

#define NPB 8192
#define NB 8
#define MQ 2048
#define FD 64
#define KN 32
#define CD 128
#define NQ (NB*MQ)
#define CAP 512
#define NCB 248                               // consumer blocks
#define NUNITS (NCB*4)                        // 992 units of 128 threads
#define UPC (NUNITS/NB)                       // 124 units per cloud
#define QITERS ((MQ + UPC - 1) / UPC)         // 17 rounds, tq = r*124+ui
#define PSTRIDE 16                            // progress padded to 64B/cloud

typedef unsigned long long ull;
typedef float v2f __attribute__((ext_vector_type(2)));

// LDS-only block barrier: orders LDS ops across the block WITHOUT draining
// vmcnt (global stores keep flying). Only LDS data (slot[]) crosses this
// barrier in the FPS loop, so lgkmcnt(0) is sufficient.
#define LDS_BARRIER() asm volatile("s_waitcnt lgkmcnt(0)\n\ts_barrier" ::: "memory")

// exact (non-FMA) squared distance, matching ((dx*dx + dy*dy) + dz*dz) in f32
__device__ __forceinline__ float dist2(float ax, float ay, float az,
                                       float bx, float by, float bz) {
    float dx = __fsub_rn(ax, bx);
    float dy = __fsub_rn(ay, by);
    float dz = __fsub_rn(az, bz);
    return __fadd_rn(__fadd_rn(__fmul_rn(dx, dx), __fmul_rn(dy, dy)), __fmul_rn(dz, dz));
}

// ---- f64-as-u64 ordered max -------------------------------------------------
// Key = (dmin_bits<<32) | ~idx. Top bit is always 0 and the f64 exponent field
// never reaches all-ones because dmin is a non-NaN f32 (<= 0x7f800000). So every
// key is a positive finite double; for positive finite doubles IEEE ordering ==
// unsigned ordering of the bits. One v_max_f64 replaces 5-op u64 cmp+cndmask.
__device__ __forceinline__ double key_as_f64(ull k) {
    return __longlong_as_double((long long)k);
}
__device__ __forceinline__ ull key_as_u64(double d) {
    return (ull)__double_as_longlong(d);
}

template <int CTRL>
__device__ __forceinline__ double dpp_max_f64_step(double key) {
    ull u = key_as_u64(key);
    int lo = (int)(unsigned)u, hi = (int)(u >> 32);
    int lo2 = __builtin_amdgcn_update_dpp(0, lo, CTRL, 0xf, 0xf, false);
    int hi2 = __builtin_amdgcn_update_dpp(0, hi, CTRL, 0xf, 0xf, false);
    double o = key_as_f64(((ull)(unsigned)hi2 << 32) | (unsigned)lo2);
    // lanes with no source get old=0 -> +0.0, which never beats a real key (>0)
    return fmax(key, o);
}

// 6-step full-wave (64-lane) max reduce via DPP; result valid in lane 63.
__device__ __forceinline__ double dpp_max_f64(double key) {
    key = dpp_max_f64_step<0x111>(key);  // row_shr:1
    key = dpp_max_f64_step<0x112>(key);  // row_shr:2
    key = dpp_max_f64_step<0x114>(key);  // row_shr:4
    key = dpp_max_f64_step<0x118>(key);  // row_shr:8
    key = dpp_max_f64_step<0x142>(key);  // row_bcast15
    key = dpp_max_f64_step<0x143>(key);  // row_bcast31
    return key;
}

// 3-step reduce when values are replicated within each 8-lane group
// (8 distinct candidates at lanes g*8..g*8+7); result valid in lane 63.
__device__ __forceinline__ double dpp_max_f64_groups8(double key) {
    key = dpp_max_f64_step<0x118>(key);  // row_shr:8
    key = dpp_max_f64_step<0x142>(key);  // row_bcast15
    key = dpp_max_f64_step<0x143>(key);  // row_bcast31
    return key;
}

__device__ __forceinline__ unsigned morton9(float x, float y, float z) {
    unsigned cx = (unsigned)min(7, max(0, (int)(x * 8.0f)));
    unsigned cy = (unsigned)min(7, max(0, (int)(y * 8.0f)));
    unsigned cz = (unsigned)min(7, max(0, (int)(z * 8.0f)));
    return (cx & 1) | ((cy & 1) << 1) | ((cz & 1) << 2)
         | ((cx & 2) << 2) | ((cy & 2) << 3) | ((cz & 2) << 4)
         | ((cx & 4) << 4) | ((cy & 4) << 5) | ((cz & 4) << 6);
}

struct FpsSlot {                       // 32 B: one wave's candidate
    ull key;                           // (dmin_bits << 32) | ~orig_idx
    float x, y, z;
    float pad[3];
};
struct FpsSM {
    float2 sxy[NPB];                   // 64 KB
    float sz[NPB];                     // 32 KB
    unsigned sidx[NPB];                // 32 KB (morton-bucketed point order)
    __align__(16) FpsSlot slot[2][8];  // 512 B double-buffered candidates
    unsigned hist[512];                // counting-sort histogram
    unsigned off[512];                 // prefix/pong buffer
};
struct UnitSM {
    float msg[KN][68];                 // 8704 B, 16-aligned (first member)
    ull buf[CAP];                      // 4096 B
    int nb[KN];
    int scnt;
    int pad;
};
union SMU {
    FpsSM f;
    UnitSM u[4];
};

__global__ __launch_bounds__(512) void mega_kernel(const float* __restrict__ xin,
                                                   const float* __restrict__ pos,
                                                   const float* __restrict__ W1,
                                                   const float* __restrict__ b1,
                                                   int* __restrict__ samp,
                                                   int* __restrict__ progress,
                                                   float* __restrict__ out) {
    __shared__ SMU sm;
    const int tid = threadIdx.x;

    if (blockIdx.x < NB) {
        // ======================= FPS producer (blocks 0..7) =======================
        // 8 waves; each owns TWO spatially-opposite 512-pt Morton regions
        // (chunks), with separate bboxes + wave-level activity votes, so the
        // typical winner wave scans 8 pts/thread instead of 16.
        const int b = blockIdx.x;
        const int wv = tid >> 6, lane = tid & 63;
        const float* p0 = pos + (size_t)b * NPB * 3;

        // ---- stage positions + morton histogram ----
        sm.f.hist[tid] = 0;
        __syncthreads();
        for (int i = tid; i < NPB; i += 512) {
            float x = p0[i * 3 + 0];
            float y = p0[i * 3 + 1];
            float z = p0[i * 3 + 2];
            sm.f.sxy[i] = make_float2(x, y);
            sm.f.sz[i] = z;
            atomicAdd(&sm.f.hist[morton9(x, y, z)], 1);
        }
        __syncthreads();

        // ---- seed "previous" slots so t==0 takes the uniform path (winner idx 0) ----
        if (tid < 8) {
            FpsSlot* d = &sm.f.slot[1][tid];
            d->key = ((ull)0x7f800000u << 32) | 0xFFFFFFFFu;
            d->x = sm.f.sxy[0].x;
            d->y = sm.f.sxy[0].y;
            d->z = sm.f.sz[0];
        }

        // ---- exclusive prefix over 512 bins (Hillis-Steele, ping-pong) ----
        unsigned hval = sm.f.hist[tid];
        unsigned* src = sm.f.hist;
        unsigned* dst = sm.f.off;
        #pragma unroll 1
        for (int d = 1; d < 512; d <<= 1) {
            unsigned v = src[tid];
            if (tid >= d) v += src[tid - d];
            __syncthreads();
            dst[tid] = v;
            __syncthreads();
            unsigned* tmp = src; src = dst; dst = tmp;
        }
        unsigned excl = src[tid] - hval;   // src holds inclusive prefix
        dst[tid] = excl;                   // dst becomes the scatter cursor
        unsigned* cursor = dst;
        __syncthreads();

        // ---- scatter: morton-bucketed point order ----
        for (int i = tid; i < NPB; i += 512) {
            float2 xy = sm.f.sxy[i];
            unsigned m = morton9(xy.x, xy.y, sm.f.sz[i]);
            unsigned p = atomicAdd(&cursor[m], 1);
            sm.f.sidx[p] = (unsigned)i;
        }
        __syncthreads();

        // ---- register staging: 2 chunks x 8 points per thread ----
        // Chunk regions {w, 15-w}: Morton top-4-bit complement -> spatially
        // opposite corners, so a pick rarely activates both chunks of one wave.
        const unsigned* sp0 = &sm.f.sidx[wv * 512 + lane * 8];
        const unsigned* sp1 = &sm.f.sidx[(15 - wv) * 512 + lane * 8];
        v2f px2[8], py2[8], pz2[8], dmin2[8];   // [0..3]=chunk0, [4..7]=chunk1
        unsigned norig[16];
        const float inf = __builtin_huge_valf();
        float ax0 = inf, ax1 = -inf, ay0 = inf, ay1 = -inf, az0 = inf, az1 = -inf;
        float ex0 = inf, ex1 = -inf, ey0 = inf, ey1 = -inf, ez0 = inf, ez1 = -inf;
        #pragma unroll
        for (int i = 0; i < 4; i++) {
            unsigned o0 = sp0[2 * i + 0];
            unsigned o1 = sp0[2 * i + 1];
            norig[2 * i + 0] = ~o0;
            norig[2 * i + 1] = ~o1;
            float2 a = sm.f.sxy[o0], c2 = sm.f.sxy[o1];
            float za = sm.f.sz[o0], zc = sm.f.sz[o1];
            px2[i] = (v2f){a.x, c2.x};
            py2[i] = (v2f){a.y, c2.y};
            pz2[i] = (v2f){za, zc};
            dmin2[i] = (v2f){inf, inf};
            ax0 = fminf(ax0, fminf(a.x, c2.x)); ax1 = fmaxf(ax1, fmaxf(a.x, c2.x));
            ay0 = fminf(ay0, fminf(a.y, c2.y)); ay1 = fmaxf(ay1, fmaxf(a.y, c2.y));
            az0 = fminf(az0, fminf(za, zc));    az1 = fmaxf(az1, fmaxf(za, zc));
        }
        #pragma unroll
        for (int i = 0; i < 4; i++) {
            unsigned o0 = sp1[2 * i + 0];
            unsigned o1 = sp1[2 * i + 1];
            norig[8 + 2 * i + 0] = ~o0;
            norig[8 + 2 * i + 1] = ~o1;
            float2 a = sm.f.sxy[o0], c2 = sm.f.sxy[o1];
            float za = sm.f.sz[o0], zc = sm.f.sz[o1];
            px2[4 + i] = (v2f){a.x, c2.x};
            py2[4 + i] = (v2f){a.y, c2.y};
            pz2[4 + i] = (v2f){za, zc};
            dmin2[4 + i] = (v2f){inf, inf};
            ex0 = fminf(ex0, fminf(a.x, c2.x)); ex1 = fmaxf(ex1, fmaxf(a.x, c2.x));
            ey0 = fminf(ey0, fminf(a.y, c2.y)); ey1 = fmaxf(ey1, fmaxf(a.y, c2.y));
            ez0 = fminf(ez0, fminf(za, zc));    ez1 = fmaxf(ez1, fmaxf(za, zc));
        }
        double mykey0 = key_as_f64((ull)0x7f800000u << 32);  // +INF -> scans at t=0
        double mykey1 = mykey0;
        ull cachedkey = 0;
        float cachedx = 0.f, cachedy = 0.f, cachedz = 0.f;
        __syncthreads();

        for (int t = 0; t < MQ; t++) {
            // ---- resolve global winner: lane-group g reads slot g only ----
            const FpsSlot* srd = &sm.f.slot[(t - 1) & 1][lane >> 3];
            ulonglong2 rv = *(const ulonglong2*)srd;   // key | (x,y)
            float gzf = srd->z;
            ull kg = rv.x;
            double krd = dpp_max_f64_groups8(key_as_f64(kg));
            ull krb = key_as_u64(krd);
            unsigned whi = (unsigned)__builtin_amdgcn_readlane((int)(krb >> 32), 63);
            unsigned wlo = (unsigned)__builtin_amdgcn_readlane((int)(unsigned)krb, 63);
            ull wk = ((ull)whi << 32) | wlo;
            int last = (int)((~wlo) & (NPB - 1));
            ull iswin = __ballot(kg == wk);
            int wl = __ffsll((long long)iswin) - 1;
            int gxi = (int)(unsigned)rv.y;
            int gyi = (int)(rv.y >> 32);
            float lx = __int_as_float(__builtin_amdgcn_readlane(gxi, wl));
            float ly = __int_as_float(__builtin_amdgcn_readlane(gyi, wl));
            float lz = __int_as_float(__builtin_amdgcn_readlane(__float_as_int(gzf), wl));

            // publisher: plain store per iter, release-publish every 16 iters.
            if (tid == 448) {
                samp[b * MQ + t] = last;
                if ((t & 15) == 15)
                    __hip_atomic_store(&progress[b * PSTRIDE], t + 1, __ATOMIC_RELEASE,
                                       __HIP_MEMORY_SCOPE_AGENT);
            }

            // per-chunk conservative lower bounds vs per-lane current max dmin
            float d0x = fmaxf(fmaxf(ax0 - lx, lx - ax1), 0.0f);
            float d0y = fmaxf(fmaxf(ay0 - ly, ly - ay1), 0.0f);
            float d0z = fmaxf(fmaxf(az0 - lz, lz - az1), 0.0f);
            float dlb0 = d0x * d0x + d0y * d0y + d0z * d0z;
            float d1x = fmaxf(fmaxf(ex0 - lx, lx - ex1), 0.0f);
            float d1y = fmaxf(fmaxf(ey0 - ly, ly - ey1), 0.0f);
            float d1z = fmaxf(fmaxf(ez0 - lz, lz - ez1), 0.0f);
            float dlb1 = d1x * d1x + d1y * d1y + d1z * d1z;
            float cm0 = __uint_as_float((unsigned)(key_as_u64(mykey0) >> 32));
            float cm1 = __uint_as_float((unsigned)(key_as_u64(mykey1) >> 32));
            bool act0 = __fmul_rn(0.999f, dlb0) < cm0;
            bool act1 = __fmul_rn(0.999f, dlb1) < cm1;
            bool wa0 = __any(act0);
            bool wa1 = __any(act1);

            if (wa0 || wa1) {
                double oldc = fmax(mykey0, mykey1);
                if (wa0 && act0) {
                    // contract(off): keep mul,mul,mul,add,add exactly like the
                    // reference (((dx*dx + dy*dy) + dz*dz)).
                    #pragma clang fp contract(off)
                    double ba = 0.0, bb = 0.0;
                    #pragma unroll
                    for (int i = 0; i < 4; i++) {
                        v2f dx = px2[i] - lx;
                        v2f dy = py2[i] - ly;
                        v2f dz = pz2[i] - lz;
                        v2f d2v = (dx * dx + dy * dy) + dz * dz;
                        float d0 = fminf(dmin2[i].x, d2v.x);
                        float d1 = fminf(dmin2[i].y, d2v.y);
                        dmin2[i] = (v2f){d0, d1};
                        double k0 = key_as_f64(((ull)__float_as_uint(d0) << 32) | norig[2 * i + 0]);
                        double k1 = key_as_f64(((ull)__float_as_uint(d1) << 32) | norig[2 * i + 1]);
                        ba = fmax(ba, k0);
                        bb = fmax(bb, k1);
                    }
                    mykey0 = fmax(ba, bb);
                }
                if (wa1 && act1) {
                    #pragma clang fp contract(off)
                    double ba = 0.0, bb = 0.0;
                    #pragma unroll
                    for (int i = 4; i < 8; i++) {
                        v2f dx = px2[i] - lx;
                        v2f dy = py2[i] - ly;
                        v2f dz = pz2[i] - lz;
                        v2f d2v = (dx * dx + dy * dy) + dz * dz;
                        float d0 = fminf(dmin2[i].x, d2v.x);
                        float d1 = fminf(dmin2[i].y, d2v.y);
                        dmin2[i] = (v2f){d0, d1};
                        double k0 = key_as_f64(((ull)__float_as_uint(d0) << 32) | norig[2 * i + 0]);
                        double k1 = key_as_f64(((ull)__float_as_uint(d1) << 32) | norig[2 * i + 1]);
                        ba = fmax(ba, k0);
                        bb = fmax(bb, k1);
                    }
                    mykey1 = fmax(ba, bb);
                }
                double comb = fmax(mykey0, mykey1);
                // skip the wave-reduce when no lane's best changed (bit-exact):
                // the cached wave max + coords are then still valid.
                if (!__all(comb == oldc)) {
                    double w = dpp_max_f64(comb);
                    ull wb = key_as_u64(w);
                    unsigned chi = (unsigned)__builtin_amdgcn_readlane((int)(wb >> 32), 63);
                    unsigned clo = (unsigned)__builtin_amdgcn_readlane((int)(unsigned)wb, 63);
                    cachedkey = ((ull)chi << 32) | clo;
                    int wi = (int)((~clo) & (NPB - 1));
                    float2 cxy = sm.f.sxy[wi];          // uniform addr -> broadcast read
                    cachedx = cxy.x;
                    cachedy = cxy.y;
                    cachedz = sm.f.sz[wi];
                }
            }
            // write (possibly cached) candidate slot for this iteration
            if (lane == 63) {
                FpsSlot* d = &sm.f.slot[t & 1][wv];
                ulonglong2 wv2;
                wv2.x = cachedkey;
                wv2.y = ((ull)(unsigned)__float_as_int(cachedy) << 32)
                      | (unsigned)__float_as_int(cachedx);
                *(ulonglong2*)d = wv2;              // ds_write_b128
                d->z = cachedz;                     // ds_write_b32
            }
            LDS_BARRIER();   // orders the LDS slots; does NOT drain global stores
        }
        return;
    }

    // ================== consumers: ball query + MLP + tail outputs ==================
    const int c = blockIdx.x - NB;         // 0..247
    const int unit = tid >> 7;             // 0..3
    const int ut = tid & 127;              // thread-in-unit
    UnitSM& U = sm.u[unit];
    const int g = c * 4 + unit;            // global unit id, 0..991
    const int b = g & 7;                   // cloud owned by this unit
    const int ui = g >> 3;                 // 0..123 slot within cloud
    const float RR = (float)(0.1 * 0.1);
    const float* P = pos + (size_t)b * NPB * 3;

    // per-channel weights, hoisted across queries
    float w[68];
    #pragma unroll
    for (int f = 0; f < 67; f++) w[f] = W1[f * CD + ut];
    w[67] = 0.0f;
    const float bias = b1[ut];

    for (int r = 0; r < QITERS; r++) {
        // pipelined mapping: round r needs FPS progress only up to 124*(r+1),
        // so consumer work overlaps FPS instead of bursting after it finishes.
        const int tq = r * UPC + ui;
        const bool active = tq < MQ;
        const int q = (b << 11) + tq;
        int s = 0;
        float qx = 0.f, qy = 0.f, qz = 0.f;

        if (active && ut == 0) {
            // single poller per unit: relaxed agent load + one acquire fence;
            // the following __syncthreads orders it for the whole unit.
            while (__hip_atomic_load(&progress[b * PSTRIDE], __ATOMIC_RELAXED,
                                     __HIP_MEMORY_SCOPE_AGENT) < tq + 1) {}
            __builtin_amdgcn_fence(__ATOMIC_ACQUIRE, "agent");
            U.scnt = 0;
        }
        __syncthreads();                                   // barrier 1

        if (active) {
            s = samp[q] & (NPB - 1);
            qx = P[s * 3 + 0]; qy = P[s * 3 + 1]; qz = P[s * 3 + 2];
            for (int p = ut; p < NPB; p += 128) {
                float xx = P[p * 3 + 0];
                float yy = P[p * 3 + 1];
                float zz = P[p * 3 + 2];
                float d2v = dist2(qx, qy, qz, xx, yy, zz);
                if (d2v <= RR) {
                    int slot = atomicAdd(&U.scnt, 1);
                    if (slot < CAP)
                        U.buf[slot] = ((ull)__float_as_uint(d2v) << 32) | (unsigned)p;
                }
            }
        }
        __syncthreads();                                   // barrier 2

        int n = 0, nk = 0;
        if (active) {
            n = U.scnt; if (n > CAP) n = CAP;
            nk = (n < KN) ? n : KN;
        }
        if (active && ut < 64) {
            if (n <= 64) {
                // fast path: 64-key bitonic sort in the unit's first wave
                ull key = (ut < n) ? U.buf[ut] : ~0ULL;
                #pragma unroll
                for (int k = 2; k <= 64; k <<= 1) {
                    #pragma unroll
                    for (int j = k >> 1; j > 0; j >>= 1) {
                        ull o = __shfl_xor(key, (unsigned)j, 64);
                        bool ascending = ((ut & k) == 0);
                        bool upper = ((ut & j) != 0);
                        bool keepMin = (ascending != upper);
                        ull mn = (o < key) ? o : key;
                        ull mx = (o < key) ? key : o;
                        key = keepMin ? mn : mx;
                    }
                }
                if (ut < nk) U.nb[ut] = ((int)(unsigned)key) & (NPB - 1);
            } else {
                // slow path (rare): nk rounds of wave-min selection
                ull ck[CAP / 64];
                #pragma unroll
                for (int i = 0; i < CAP / 64; i++) {
                    int sl = ut + i * 64;
                    ck[i] = (sl < n) ? U.buf[sl] : ~0ULL;
                }
                for (int rr = 0; rr < nk; rr++) {
                    ull lm = ck[0];
                    int li = 0;
                    #pragma unroll
                    for (int i = 1; i < CAP / 64; i++) {
                        if (ck[i] < lm) { lm = ck[i]; li = i; }
                    }
                    ull gm = lm;
                    #pragma unroll
                    for (int off = 1; off < 64; off <<= 1) {
                        ull o = __shfl_xor(gm, off, 64);
                        gm = (o < gm) ? o : gm;
                    }
                    ull won = __ballot(lm == gm);
                    int wlane = __ffsll((long long)won) - 1;
                    if (ut == wlane) ck[li] = ~0ULL;
                    if (ut == 0) U.nb[rr] = ((int)(unsigned)gm) & (NPB - 1);
                }
            }
        }
        __syncthreads();                                   // barrier 3

        if (active) {
            const int lane64 = ut & 63, half = ut >> 6;
            for (int k = half; k < nk; k += 2) {
                int p = U.nb[k];
                U.msg[k][lane64] = xin[((size_t)(b * NPB + p)) * FD + lane64];
            }
            if (ut < nk) {
                int p = U.nb[ut];
                U.msg[ut][64] = __fsub_rn(P[p * 3 + 0], qx);
                U.msg[ut][65] = __fsub_rn(P[p * 3 + 1], qy);
                U.msg[ut][66] = __fsub_rn(P[p * 3 + 2], qz);
                U.msg[ut][67] = 0.0f;
            }
        }
        __syncthreads();                                   // barrier 4

        if (active) {
            float acc = 0.0f;   // relu >= 0 and nk >= 1 (self), so 0 is the max identity
            for (int k = 0; k < nk; k++) {
                float s0 = 0.f, s1 = 0.f, s2 = 0.f, s3 = 0.f;
                #pragma unroll
                for (int f4 = 0; f4 < 17; f4++) {
                    float4 mv = *(const float4*)&U.msg[k][f4 * 4];
                    s0 = fmaf(mv.x, w[f4 * 4 + 0], s0);
                    s1 = fmaf(mv.y, w[f4 * 4 + 1], s1);
                    s2 = fmaf(mv.z, w[f4 * 4 + 2], s2);
                    s3 = fmaf(mv.w, w[f4 * 4 + 3], s3);
                }
                float h = (s0 + s1) + (s2 + s3) + bias;
                h = fmaxf(h, 0.0f);
                acc = fmaxf(acc, h);
            }
            out[(size_t)q * CD + ut] = acc;
            if (ut == 0) {
                float* qp = out + (size_t)NQ * CD;
                qp[q * 3 + 0] = qx;
                qp[q * 3 + 1] = qy;
                qp[q * 3 + 2] = qz;
                float* bo = qp + (size_t)NQ * 3;
                bo[q] = (float)b;
                float* io = bo + NQ;
                io[q] = (float)(b * NPB + s);
            }
        }
    }
}

extern "C" void kernel_launch(void* const* d_in, const int* in_sizes, int n_in,
                              void* d_out, int out_size, void* d_ws, size_t ws_size,
                              hipStream_t stream) {
    const float* x   = (const float*)d_in[0];
    const float* pos = (const float*)d_in[1];
    const float* W1  = (const float*)d_in[3];
    const float* b1  = (const float*)d_in[4];
    float* out = (float*)d_out;

    int* samp = (int*)d_ws;                     // NQ ints (64B-aligned base)
    int* progress = samp + NQ;                  // NB*PSTRIDE ints (1 line/cloud)

    hipMemsetAsync(progress, 0, NB * PSTRIDE * sizeof(int), stream);
    mega_kernel<<<NB + NCB, 512, 0, stream>>>(x, pos, W1, b1, samp, progress, out);
}

// Round 9
// 1422.422 us; speedup vs baseline: 2.0158x; 1.0695x over previous
//
#include <hip/hip_runtime.h>

#define NPB 8192
#define NB 8
#define MQ 2048
#define FD 64
#define KN 32
#define CD 128
#define NQ (NB*MQ)
#define CAP 512
#define NCB 248                               // consumer blocks
#define NUNITS (NCB*4)                        // 992 units of 128 threads
#define UPC (NUNITS/NB)                       // 124 units per cloud
#define QITERS ((MQ + UPC - 1) / UPC)         // 17 rounds, tq = r*124+ui
#define PSTRIDE 16                            // progress padded to 64B/cloud

typedef unsigned long long ull;
typedef float v2f __attribute__((ext_vector_type(2)));

// LDS-only block barrier: orders LDS ops across the block WITHOUT draining
// vmcnt (global stores keep flying). Only LDS data (slot[]) crosses this
// barrier in the FPS loop, so lgkmcnt(0) is sufficient.
#define LDS_BARRIER() asm volatile("s_waitcnt lgkmcnt(0)\n\ts_barrier" ::: "memory")

// exact (non-FMA) squared distance, matching ((dx*dx + dy*dy) + dz*dz) in f32
__device__ __forceinline__ float dist2(float ax, float ay, float az,
                                       float bx, float by, float bz) {
    float dx = __fsub_rn(ax, bx);
    float dy = __fsub_rn(ay, by);
    float dz = __fsub_rn(az, bz);
    return __fadd_rn(__fadd_rn(__fmul_rn(dx, dx), __fmul_rn(dy, dy)), __fmul_rn(dz, dz));
}

// ---- f64-as-u64 ordered max -------------------------------------------------
// Key = (dmin_bits<<32) | ~idx. Top bit is always 0 and the f64 exponent field
// never reaches all-ones because dmin is a non-NaN f32 (<= 0x7f800000). So every
// key is a positive finite double; for positive finite doubles IEEE ordering ==
// unsigned ordering of the bits. One v_max_f64 replaces 5-op u64 cmp+cndmask.
// Keys are also never zero (~idx != 0), so f64 == is bit-exact equality.
__device__ __forceinline__ double key_as_f64(ull k) {
    return __longlong_as_double((long long)k);
}
__device__ __forceinline__ ull key_as_u64(double d) {
    return (ull)__double_as_longlong(d);
}

template <int CTRL>
__device__ __forceinline__ double dpp_max_f64_step(double key) {
    ull u = key_as_u64(key);
    int lo = (int)(unsigned)u, hi = (int)(u >> 32);
    int lo2 = __builtin_amdgcn_update_dpp(0, lo, CTRL, 0xf, 0xf, false);
    int hi2 = __builtin_amdgcn_update_dpp(0, hi, CTRL, 0xf, 0xf, false);
    double o = key_as_f64(((ull)(unsigned)hi2 << 32) | (unsigned)lo2);
    // lanes with no source get old=0 -> +0.0, which never beats a real key (>0)
    return fmax(key, o);
}

// 6-step full-wave (64-lane) max reduce via DPP; result valid in lane 63.
__device__ __forceinline__ double dpp_max_f64(double key) {
    key = dpp_max_f64_step<0x111>(key);  // row_shr:1
    key = dpp_max_f64_step<0x112>(key);  // row_shr:2
    key = dpp_max_f64_step<0x114>(key);  // row_shr:4
    key = dpp_max_f64_step<0x118>(key);  // row_shr:8
    key = dpp_max_f64_step<0x142>(key);  // row_bcast15
    key = dpp_max_f64_step<0x143>(key);  // row_bcast31
    return key;
}

// 3-step reduce when values are replicated within each 8-lane group
// (8 distinct candidates at lanes g*8..g*8+7); result valid in lane 63.
__device__ __forceinline__ double dpp_max_f64_groups8(double key) {
    key = dpp_max_f64_step<0x118>(key);  // row_shr:8
    key = dpp_max_f64_step<0x142>(key);  // row_bcast15
    key = dpp_max_f64_step<0x143>(key);  // row_bcast31
    return key;
}

__device__ __forceinline__ unsigned morton9(float x, float y, float z) {
    unsigned cx = (unsigned)min(7, max(0, (int)(x * 8.0f)));
    unsigned cy = (unsigned)min(7, max(0, (int)(y * 8.0f)));
    unsigned cz = (unsigned)min(7, max(0, (int)(z * 8.0f)));
    return (cx & 1) | ((cy & 1) << 1) | ((cz & 1) << 2)
         | ((cx & 2) << 2) | ((cy & 2) << 3) | ((cz & 2) << 4)
         | ((cx & 4) << 4) | ((cy & 4) << 5) | ((cz & 4) << 6);
}

struct FpsSlot {                       // keys-only, padded to 32 B (2-way bank
    ull key;                           // aliasing across the 8 slots = free)
    ull pad[3];
};
struct FpsSM {
    float2 sxy[NPB];                   // 64 KB
    float sz[NPB];                     // 32 KB
    unsigned sidx[NPB];                // 32 KB (morton-bucketed point order)
    __align__(16) FpsSlot slot[2][8];  // 512 B double-buffered candidate keys
    unsigned hist[512];                // counting-sort histogram
    unsigned off[512];                 // prefix/pong buffer
};
struct UnitSM {
    float msg[KN][68];                 // 8704 B, 16-aligned (first member)
    ull buf[CAP];                      // 4096 B
    int nb[KN];
    int scnt;
    int pad;
};
union SMU {
    FpsSM f;
    UnitSM u[4];
};

__global__ __launch_bounds__(512) void mega_kernel(const float* __restrict__ xin,
                                                   const float* __restrict__ pos,
                                                   const float* __restrict__ W1,
                                                   const float* __restrict__ b1,
                                                   int* __restrict__ samp,
                                                   int* __restrict__ progress,
                                                   float* __restrict__ out) {
    __shared__ SMU sm;
    const int tid = threadIdx.x;

    if (blockIdx.x < NB) {
        // ======================= FPS producer (blocks 0..7) =======================
        const int b = blockIdx.x;
        const int wv = tid >> 6, lane = tid & 63;
        const float* p0 = pos + (size_t)b * NPB * 3;

        // ---- stage positions + morton histogram ----
        sm.f.hist[tid] = 0;
        __syncthreads();
        for (int i = tid; i < NPB; i += 512) {
            float x = p0[i * 3 + 0];
            float y = p0[i * 3 + 1];
            float z = p0[i * 3 + 2];
            sm.f.sxy[i] = make_float2(x, y);
            sm.f.sz[i] = z;
            atomicAdd(&sm.f.hist[morton9(x, y, z)], 1);
        }
        __syncthreads();

        // ---- seed "previous" slots so t==0 takes the uniform path (winner idx 0) ----
        if (tid < 8)
            sm.f.slot[1][tid].key = ((ull)0x7f800000u << 32) | 0xFFFFFFFFu;

        // ---- exclusive prefix over 512 bins (Hillis-Steele, ping-pong) ----
        unsigned hval = sm.f.hist[tid];
        unsigned* src = sm.f.hist;
        unsigned* dst = sm.f.off;
        #pragma unroll 1
        for (int d = 1; d < 512; d <<= 1) {
            unsigned v = src[tid];
            if (tid >= d) v += src[tid - d];
            __syncthreads();
            dst[tid] = v;
            __syncthreads();
            unsigned* tmp = src; src = dst; dst = tmp;
        }
        unsigned excl = src[tid] - hval;   // src holds inclusive prefix
        dst[tid] = excl;                   // dst becomes the scatter cursor
        unsigned* cursor = dst;
        __syncthreads();

        // ---- scatter: morton-bucketed point order ----
        for (int i = tid; i < NPB; i += 512) {
            float2 xy = sm.f.sxy[i];
            unsigned m = morton9(xy.x, xy.y, sm.f.sz[i]);
            unsigned p = atomicAdd(&cursor[m], 1);
            sm.f.sidx[p] = (unsigned)i;
        }
        __syncthreads();

        // ---- register staging: 16 spatially-compact points per thread ----
        // Octant->wave permutation: waves {s, s+4} share a SIMD; give them
        // diagonally opposite octants so they are rarely both active.
        const int perm8[8] = {0, 1, 2, 3, 7, 6, 5, 4};
        const unsigned* sp = &sm.f.sidx[perm8[wv] * 1024 + lane * 16];
        v2f px2[8], py2[8], pz2[8], dmin2[8];
        unsigned norig[16];
        const float inf = __builtin_huge_valf();
        float bx0 = inf, bx1 = -inf;
        float by0 = inf, by1 = -inf;
        float bz0 = inf, bz1 = -inf;
        #pragma unroll
        for (int i = 0; i < 8; i++) {
            unsigned o0 = sp[2 * i + 0];
            unsigned o1 = sp[2 * i + 1];
            norig[2 * i + 0] = ~o0;
            norig[2 * i + 1] = ~o1;
            float2 a = sm.f.sxy[o0], c2 = sm.f.sxy[o1];
            float za = sm.f.sz[o0], zc = sm.f.sz[o1];
            px2[i] = (v2f){a.x, c2.x};
            py2[i] = (v2f){a.y, c2.y};
            pz2[i] = (v2f){za, zc};
            dmin2[i] = (v2f){inf, inf};
            bx0 = fminf(bx0, fminf(a.x, c2.x)); bx1 = fmaxf(bx1, fmaxf(a.x, c2.x));
            by0 = fminf(by0, fminf(a.y, c2.y)); by1 = fmaxf(by1, fmaxf(a.y, c2.y));
            bz0 = fminf(bz0, fminf(za, zc));    bz1 = fmaxf(bz1, fmaxf(za, zc));
        }
        double mykey = key_as_f64((ull)0x7f800000u << 32);  // dmin=+INF -> scans at t=0
        double wavekey = mykey;            // lane 63: wave's reduced candidate key
        __syncthreads();

        for (int t = 0; t < MQ; t++) {
            // ---- resolve winner index: lane-group g reads slot-key g only ----
            ull kg = sm.f.slot[(t - 1) & 1][lane >> 3].key;
            double krd = dpp_max_f64_groups8(key_as_f64(kg));
            unsigned wlo = (unsigned)__builtin_amdgcn_readlane(
                (int)(unsigned)key_as_u64(krd), 63);
            int last = (int)((~wlo) & (NPB - 1));

            // winner coords: uniform-address broadcast read (no per-slot coords)
            float2 lxy = sm.f.sxy[last];
            float lx = lxy.x, ly = lxy.y, lz = sm.f.sz[last];

            // publisher (wave 7 lane 0): plain samp store per iter. Release at
            // t%16==0 publishes progress=t (covers samp[0..t-1], all issued >=1
            // iteration ago -> the vmcnt(0) release drain is ~free).
            if (tid == 448) {
                if (t && (t & 15) == 0)
                    __hip_atomic_store(&progress[b * PSTRIDE], t, __ATOMIC_RELEASE,
                                       __HIP_MEMORY_SCOPE_AGENT);
                samp[b * MQ + t] = last;
            }

            // conservative lower bound of d2(last, any point in this thread's bbox)
            float ddx = fmaxf(fmaxf(bx0 - lx, lx - bx1), 0.0f);
            float ddy = fmaxf(fmaxf(by0 - ly, ly - by1), 0.0f);
            float ddz = fmaxf(fmaxf(bz0 - lz, lz - bz1), 0.0f);
            float dlb = ddx * ddx + ddy * ddy + ddz * ddz;
            float cm = __uint_as_float((unsigned)(key_as_u64(mykey) >> 32));
            bool act = __fmul_rn(0.999f, dlb) < cm;

            if (__any(act)) {
                double oldkey = mykey;
                if (act) {
                    // contract(off): keep mul,mul,mul,add,add exactly like the
                    // reference (((dx*dx + dy*dy) + dz*dz)).
                    #pragma clang fp contract(off)
                    double ba = 0.0, bb = 0.0;
                    #pragma unroll
                    for (int i = 0; i < 8; i++) {
                        v2f dx = px2[i] - lx;
                        v2f dy = py2[i] - ly;
                        v2f dz = pz2[i] - lz;
                        v2f d2v = (dx * dx + dy * dy) + dz * dz;
                        float d0 = fminf(dmin2[i].x, d2v.x);
                        float d1 = fminf(dmin2[i].y, d2v.y);
                        dmin2[i] = (v2f){d0, d1};
                        double k0 = key_as_f64(((ull)__float_as_uint(d0) << 32) | norig[2 * i + 0]);
                        double k1 = key_as_f64(((ull)__float_as_uint(d1) << 32) | norig[2 * i + 1]);
                        ba = fmax(ba, k0);
                        bb = fmax(bb, k1);
                    }
                    mykey = fmax(ba, bb);
                }
                // skip the wave-reduce when no lane's best changed (bit-exact;
                // keys are positive finite and never zero): lane 63's cached
                // wavekey is then still the wave max.
                if (!__all(mykey == oldkey))
                    wavekey = dpp_max_f64(mykey);
            }
            // lane 63 writes its reduced register directly — no readlane, no
            // coord resolve, no tail LDS read.
            if (lane == 63)
                sm.f.slot[t & 1][wv].key = key_as_u64(wavekey);
            LDS_BARRIER();   // orders the LDS slots; does NOT drain global stores
        }
        // final publish: cover samp[0..MQ-1] (one-time vmcnt drain, off the loop)
        if (tid == 448)
            __hip_atomic_store(&progress[b * PSTRIDE], MQ, __ATOMIC_RELEASE,
                               __HIP_MEMORY_SCOPE_AGENT);
        return;
    }

    // ================== consumers: ball query + MLP + tail outputs ==================
    const int c = blockIdx.x - NB;         // 0..247
    const int unit = tid >> 7;             // 0..3
    const int ut = tid & 127;              // thread-in-unit
    UnitSM& U = sm.u[unit];
    const int g = c * 4 + unit;            // global unit id, 0..991
    const int b = g & 7;                   // cloud owned by this unit
    const int ui = g >> 3;                 // 0..123 slot within cloud
    const float RR = (float)(0.1 * 0.1);
    const float* P = pos + (size_t)b * NPB * 3;

    // per-channel weights, hoisted across queries
    float w[68];
    #pragma unroll
    for (int f = 0; f < 67; f++) w[f] = W1[f * CD + ut];
    w[67] = 0.0f;
    const float bias = b1[ut];

    for (int r = 0; r < QITERS; r++) {
        // pipelined mapping: round r needs FPS progress only up to 124*(r+1),
        // so consumer work overlaps FPS instead of bursting after it finishes.
        const int tq = r * UPC + ui;
        const bool active = tq < MQ;
        const int q = (b << 11) + tq;
        int s = 0;
        float qx = 0.f, qy = 0.f, qz = 0.f;

        if (active && ut == 0) {
            // single poller per unit: relaxed agent load + one acquire fence;
            // the following __syncthreads orders it for the whole unit.
            while (__hip_atomic_load(&progress[b * PSTRIDE], __ATOMIC_RELAXED,
                                     __HIP_MEMORY_SCOPE_AGENT) < tq + 1) {}
            __builtin_amdgcn_fence(__ATOMIC_ACQUIRE, "agent");
            U.scnt = 0;
        }
        __syncthreads();                                   // barrier 1

        if (active) {
            s = samp[q] & (NPB - 1);
            qx = P[s * 3 + 0]; qy = P[s * 3 + 1]; qz = P[s * 3 + 2];
            for (int p = ut; p < NPB; p += 128) {
                float xx = P[p * 3 + 0];
                float yy = P[p * 3 + 1];
                float zz = P[p * 3 + 2];
                float d2v = dist2(qx, qy, qz, xx, yy, zz);
                if (d2v <= RR) {
                    int slot = atomicAdd(&U.scnt, 1);
                    if (slot < CAP)
                        U.buf[slot] = ((ull)__float_as_uint(d2v) << 32) | (unsigned)p;
                }
            }
        }
        __syncthreads();                                   // barrier 2

        int n = 0, nk = 0;
        if (active) {
            n = U.scnt; if (n > CAP) n = CAP;
            nk = (n < KN) ? n : KN;
        }
        if (active && ut < 64) {
            if (n <= 64) {
                // fast path: 64-key bitonic sort in the unit's first wave
                ull key = (ut < n) ? U.buf[ut] : ~0ULL;
                #pragma unroll
                for (int k = 2; k <= 64; k <<= 1) {
                    #pragma unroll
                    for (int j = k >> 1; j > 0; j >>= 1) {
                        ull o = __shfl_xor(key, (unsigned)j, 64);
                        bool ascending = ((ut & k) == 0);
                        bool upper = ((ut & j) != 0);
                        bool keepMin = (ascending != upper);
                        ull mn = (o < key) ? o : key;
                        ull mx = (o < key) ? key : o;
                        key = keepMin ? mn : mx;
                    }
                }
                if (ut < nk) U.nb[ut] = ((int)(unsigned)key) & (NPB - 1);
            } else {
                // slow path (rare): nk rounds of wave-min selection
                ull ck[CAP / 64];
                #pragma unroll
                for (int i = 0; i < CAP / 64; i++) {
                    int sl = ut + i * 64;
                    ck[i] = (sl < n) ? U.buf[sl] : ~0ULL;
                }
                for (int rr = 0; rr < nk; rr++) {
                    ull lm = ck[0];
                    int li = 0;
                    #pragma unroll
                    for (int i = 1; i < CAP / 64; i++) {
                        if (ck[i] < lm) { lm = ck[i]; li = i; }
                    }
                    ull gm = lm;
                    #pragma unroll
                    for (int off = 1; off < 64; off <<= 1) {
                        ull o = __shfl_xor(gm, off, 64);
                        gm = (o < gm) ? o : gm;
                    }
                    ull won = __ballot(lm == gm);
                    int wlane = __ffsll((long long)won) - 1;
                    if (ut == wlane) ck[li] = ~0ULL;
                    if (ut == 0) U.nb[rr] = ((int)(unsigned)gm) & (NPB - 1);
                }
            }
        }
        __syncthreads();                                   // barrier 3

        if (active) {
            const int lane64 = ut & 63, half = ut >> 6;
            for (int k = half; k < nk; k += 2) {
                int p = U.nb[k];
                U.msg[k][lane64] = xin[((size_t)(b * NPB + p)) * FD + lane64];
            }
            if (ut < nk) {
                int p = U.nb[ut];
                U.msg[ut][64] = __fsub_rn(P[p * 3 + 0], qx);
                U.msg[ut][65] = __fsub_rn(P[p * 3 + 1], qy);
                U.msg[ut][66] = __fsub_rn(P[p * 3 + 2], qz);
                U.msg[ut][67] = 0.0f;
            }
        }
        __syncthreads();                                   // barrier 4

        if (active) {
            float acc = 0.0f;   // relu >= 0 and nk >= 1 (self), so 0 is the max identity
            for (int k = 0; k < nk; k++) {
                float s0 = 0.f, s1 = 0.f, s2 = 0.f, s3 = 0.f;
                #pragma unroll
                for (int f4 = 0; f4 < 17; f4++) {
                    float4 mv = *(const float4*)&U.msg[k][f4 * 4];
                    s0 = fmaf(mv.x, w[f4 * 4 + 0], s0);
                    s1 = fmaf(mv.y, w[f4 * 4 + 1], s1);
                    s2 = fmaf(mv.z, w[f4 * 4 + 2], s2);
                    s3 = fmaf(mv.w, w[f4 * 4 + 3], s3);
                }
                float h = (s0 + s1) + (s2 + s3) + bias;
                h = fmaxf(h, 0.0f);
                acc = fmaxf(acc, h);
            }
            out[(size_t)q * CD + ut] = acc;
            if (ut == 0) {
                float* qp = out + (size_t)NQ * CD;
                qp[q * 3 + 0] = qx;
                qp[q * 3 + 1] = qy;
                qp[q * 3 + 2] = qz;
                float* bo = qp + (size_t)NQ * 3;
                bo[q] = (float)b;
                float* io = bo + NQ;
                io[q] = (float)(b * NPB + s);
            }
        }
    }
}

extern "C" void kernel_launch(void* const* d_in, const int* in_sizes, int n_in,
                              void* d_out, int out_size, void* d_ws, size_t ws_size,
                              hipStream_t stream) {
    const float* x   = (const float*)d_in[0];
    const float* pos = (const float*)d_in[1];
    const float* W1  = (const float*)d_in[3];
    const float* b1  = (const float*)d_in[4];
    float* out = (float*)d_out;

    int* samp = (int*)d_ws;                     // NQ ints (64B-aligned base)
    int* progress = samp + NQ;                  // NB*PSTRIDE ints (1 line/cloud)

    hipMemsetAsync(progress, 0, NB * PSTRIDE * sizeof(int), stream);
    mega_kernel<<<NB + NCB, 512, 0, stream>>>(x, pos, W1, b1, samp, progress, out);
}